// Round 8
// baseline (238.060 us; speedup 1.0000x reference)
//
#include <hip/hip_runtime.h>

// Router: out[t] = x[t] @ W[split[t]] + b[split[t]]
// N=262144, D=128, E=8. fp32 in/out, bf16 MFMA.
// R8: zero-barrier wave-autonomous kernel. Each wave: 64 consecutive tokens
// x 32 cols. In-wave bucketing via ballot (scalar cnt/start), slot->row map
// via one ds_permute (register-only), per-tile row fetch via ds_bpermute.
// No __shared__ arrays, no __syncthreads, no phase-lock: every wave is an
// independent load->mfma->store stream; 4 waves/block share the L1-hot
// 32KB x-window. B-frags reloaded per expert-switch from L2-resident Wt.

typedef __bf16 bf16x8 __attribute__((ext_vector_type(8)));
typedef unsigned short u16x8 __attribute__((ext_vector_type(8)));
typedef float f32x4 __attribute__((ext_vector_type(4)));

__device__ __forceinline__ unsigned short f2bf(float f) {
    unsigned u = __builtin_bit_cast(unsigned, f);
    u += 0x7FFFu + ((u >> 16) & 1u);   // RNE
    return (unsigned short)(u >> 16);
}

// Transpose + convert W[e][f][g] (f32) -> Wt[e][g][f] (bf16).
__global__ void k_wt(const float* __restrict__ W, unsigned short* __restrict__ Wt) {
    __shared__ float T[16][132];
    int e = blockIdx.x >> 3;
    int g0 = (blockIdx.x & 7) << 4;
    const float* We = W + e * 128 * 128;
    #pragma unroll
    for (int i = 0; i < 2; ++i) {
        int idx = i * 256 + threadIdx.x;
        int f = idx >> 2, q = idx & 3;
        float4 v = *(const float4*)(We + f * 128 + g0 + q * 4);
        T[q * 4 + 0][f] = v.x; T[q * 4 + 1][f] = v.y;
        T[q * 4 + 2][f] = v.z; T[q * 4 + 3][f] = v.w;
    }
    __syncthreads();
    int g = threadIdx.x >> 4, fc = threadIdx.x & 15;
    u16x8 o;
    #pragma unroll
    for (int j = 0; j < 8; ++j) o[j] = f2bf(T[g][fc * 8 + j]);
    *(u16x8*)(Wt + ((e * 128 + g0 + g) * 128 + fc * 8)) = o;
}

#define WTOK 64    // tokens per wave (= per block window)

__global__ __launch_bounds__(256) void k_moe(
    const float* __restrict__ x, const int* __restrict__ split,
    const float* __restrict__ bias, const unsigned short* __restrict__ Wt,
    float* __restrict__ out) {

    const int tid = threadIdx.x;
    const int lane = tid & 63;
    const int w = tid >> 6;              // col-slice 0..3 (32 cols each)
    const int l15 = lane & 15, lq = lane >> 4;
    const int col0 = w * 32;
    const long t0 = (long)blockIdx.x * WTOK;
    const float* xw = x + t0 * 128;

    // ---- in-wave bucketing (all scalar except rank/slot) ----
    int ev = split[t0 + lane];
    const unsigned long long below = (1ull << lane) - 1;
    int rank = 0;
    int cnt[8], start[8];
    int run = 0;
    #pragma unroll
    for (int ee = 0; ee < 8; ++ee) {
        unsigned long long m = __ballot(ev == ee);
        if (ev == ee) rank = (int)__popcll(m & below);
        cnt[ee] = (int)__popcll(m);           // wave-uniform (SGPR)
        start[ee] = run; run += cnt[ee];
    }
    int slot = start[ev] + rank;              // bijection lane -> slot
    // lane s receives the local row index of bucket slot s (register-only)
    int tokslot = __builtin_amdgcn_ds_permute(slot << 2, lane);

    // ---- per-expert tiles ----
    #pragma unroll
    for (int ee = 0; ee < 8; ++ee) {
        int c = cnt[ee];
        if (c == 0) continue;

        // B fragments for this expert, this wave's 32 cols (L1/L2-hot)
        bf16x8 bfr0[4], bfr1[4];
        #pragma unroll
        for (int kk = 0; kk < 4; ++kk) {
            bfr0[kk] = *(const bf16x8*)(Wt + (ee * 128 + col0 + l15) * 128 + kk * 32 + lq * 8);
            bfr1[kk] = *(const bf16x8*)(Wt + (ee * 128 + col0 + 16 + l15) * 128 + kk * 32 + lq * 8);
        }
        float bv0 = bias[ee * 128 + col0 + l15];
        float bv1 = bias[ee * 128 + col0 + 16 + l15];

        int sE = start[ee];
        for (int rb = sE; rb < sE + c; rb += 16) {
            int lim = sE + c - rb; lim = lim < 16 ? lim : 16;

            // A rows for this tile (slots rb..rb+15 -> local token rows)
            int idx = rb + l15; idx = idx > 63 ? 63 : idx;
            int rowA = __builtin_amdgcn_ds_bpermute(idx << 2, tokslot);

            // gather + cvt: lane(l15,lq) reads x[rowA][lq*8 + kk*32 ..+8)
            const float* xr = xw + rowA * 128 + lq * 8;
            f32x4 acc0 = {0.f, 0.f, 0.f, 0.f}, acc1 = {0.f, 0.f, 0.f, 0.f};
            #pragma unroll
            for (int kk = 0; kk < 4; ++kk) {
                float4 lo = *(const float4*)(xr + kk * 32);
                float4 hi = *(const float4*)(xr + kk * 32 + 4);
                u16x8 u;
                u[0] = f2bf(lo.x); u[1] = f2bf(lo.y); u[2] = f2bf(lo.z); u[3] = f2bf(lo.w);
                u[4] = f2bf(hi.x); u[5] = f2bf(hi.y); u[6] = f2bf(hi.z); u[7] = f2bf(hi.w);
                bf16x8 a = __builtin_bit_cast(bf16x8, u);
                acc0 = __builtin_amdgcn_mfma_f32_16x16x32_bf16(a, bfr0[kk], acc0, 0, 0, 0);
                acc1 = __builtin_amdgcn_mfma_f32_16x16x32_bf16(a, bfr1[kk], acc1, 0, 0, 0);
            }

            // stores: D col=l15, row=lq*4+r; slot rb+lq*4+r -> token row
            #pragma unroll
            for (int r = 0; r < 4; ++r) {
                int ss = rb + lq * 4 + r; ss = ss > 63 ? 63 : ss;
                int rowS = __builtin_amdgcn_ds_bpermute(ss << 2, tokslot);
                if (lq * 4 + r < lim) {
                    float* o = out + (t0 + rowS) * 128 + col0 + l15;
                    o[0]  = acc0[r] + bv0;
                    o[16] = acc1[r] + bv1;
                }
            }
        }
    }
}

extern "C" void kernel_launch(void* const* d_in, const int* in_sizes, int n_in,
                              void* d_out, int out_size, void* d_ws, size_t ws_size,
                              hipStream_t stream) {
    const float* x     = (const float*)d_in[0];
    const int*   split = (const int*)d_in[1];
    const float* W     = (const float*)d_in[2];
    const float* bias  = (const float*)d_in[3];
    float* out = (float*)d_out;

    int n = in_sizes[1];                      // 262144
    unsigned short* Wt = (unsigned short*)d_ws;   // 8*128*128 bf16 = 256 KB

    k_wt<<<64, 256, 0, stream>>>(W, Wt);
    k_moe<<<n / WTOK, 256, 0, stream>>>(x, split, bias, Wt, out);
}

// Round 10
// 86.709 us; speedup vs baseline: 2.7455x; 2.7455x over previous
//
#include <hip/hip_runtime.h>

// Router: out[t] = x[t] @ W[split[t]] + b[split[t]]
// N=262144, D=128, E=8. fp32 in/out, bf16 MFMA.
// R10 = R9 with the A-read double-indirection fixed: SCATTER stores token
// row's data at bucketed slot s=destR[row], so COMPUTE must read A[slot]
// directly (R9 wrongly read A[trowR[slot]]). trowR is used ONLY for the
// output store address. Persistent 1-block/CU pipeline, zero in-loop global
// loads besides xv prefetch; barriers are s_barrier + lgkmcnt(0) only.

typedef __bf16 bf16x8 __attribute__((ext_vector_type(8)));
typedef float f32x4 __attribute__((ext_vector_type(4)));

__device__ __forceinline__ unsigned short f2bf(float f) {
    unsigned u = __builtin_bit_cast(unsigned, f);
    u += 0x7FFFu + ((u >> 16) & 1u);   // RNE
    return (unsigned short)(u >> 16);
}
__device__ __forceinline__ unsigned pack2(float a, float b) {
    return (unsigned)f2bf(a) | ((unsigned)f2bf(b) << 16);
}

// Transpose + convert W[e][f][g] (f32) -> Wt[e][g][f] (bf16).
__global__ void k_wt(const float* __restrict__ W, unsigned short* __restrict__ Wt) {
    __shared__ float T[16][132];
    int e = blockIdx.x >> 3;
    int g0 = (blockIdx.x & 7) << 4;
    const float* We = W + e * 128 * 128;
    #pragma unroll
    for (int i = 0; i < 2; ++i) {
        int idx = i * 256 + threadIdx.x;
        int f = idx >> 2, q = idx & 3;
        float4 v = *(const float4*)(We + f * 128 + g0 + q * 4);
        T[q * 4 + 0][f] = v.x; T[q * 4 + 1][f] = v.y;
        T[q * 4 + 2][f] = v.z; T[q * 4 + 3][f] = v.w;
    }
    __syncthreads();
    int g = threadIdx.x >> 4, fc = threadIdx.x & 15;
    unsigned short o[8];
    #pragma unroll
    for (int j = 0; j < 8; ++j) o[j] = f2bf(T[g][fc * 8 + j]);
    #pragma unroll
    for (int j = 0; j < 4; ++j)
        ((unsigned*)(Wt + (e * 128 + g0 + g) * 128 + fc * 8))[j] =
            (unsigned)o[2 * j] | ((unsigned)o[2 * j + 1] << 16);
}

#define NTOK 128
#define GRID 256
#define ITERS 8    // (262144 / 128) / 256

__global__ __launch_bounds__(512) void k_fused(
    const float* __restrict__ x, const int* __restrict__ split,
    const float* __restrict__ bias, const unsigned short* __restrict__ Wt,
    float* __restrict__ out) {

    __shared__ unsigned short A[2][NTOK * 128];   // 2 x 32 KB bf16, bucketed+swizzled
    __shared__ int sSplit[ITERS * NTOK];          // all 8 windows' split (4 KB)
    __shared__ int destR[4][NTOK], trowR[4][NTOK];
    __shared__ int cntR[4][8], startR[4][8];

    const int tid = threadIdx.x;
    const int lane = tid & 63, w = tid >> 6;
    const int l15 = lane & 15, lq = lane >> 4;
    const int win0 = (int)blockIdx.x * ITERS;

    // ---- prologue-only global loads: all-expert B frags + bias ----
    bf16x8 bf_[8][4];
    float bv_[8];
    #pragma unroll
    for (int ee = 0; ee < 8; ++ee) {
        #pragma unroll
        for (int kk = 0; kk < 4; ++kk)
            bf_[ee][kk] = *(const bf16x8*)(Wt + (ee * 128 + w * 16 + l15) * 128 + kk * 32 + lq * 8);
        bv_[ee] = bias[ee * 128 + w * 16 + l15];
    }

    float4 xv[8];
    auto XISSUE = [&](int t) {
        const float* xb = x + (long)(win0 + t) * NTOK * 128;
        #pragma unroll
        for (int rr = 0; rr < 8; ++rr)
            xv[rr] = *(const float4*)(xb + (rr * 512 + tid) * 4);
        __builtin_amdgcn_sched_barrier(0);   // pin issue point (don't sink)
    };

    auto BARRIER = [&]() {
        asm volatile("s_waitcnt lgkmcnt(0)" ::: "memory");
        __builtin_amdgcn_s_barrier();
    };

    // wave-0-only: bucket window lw's 128 tokens (2 ballot rounds), write ring
    auto META = [&](int lw) {
        const int r = lw & 3;
        const unsigned long long below = (1ull << lane) - 1;
        int basev[8];
        #pragma unroll
        for (int ee = 0; ee < 8; ++ee) basev[ee] = 0;
        int evk[2], rkk[2];
        #pragma unroll
        for (int ro = 0; ro < 2; ++ro) {
            int ev = sSplit[lw * NTOK + ro * 64 + lane];
            int rank = 0;
            #pragma unroll
            for (int ee = 0; ee < 8; ++ee) {
                unsigned long long m = __ballot(ev == ee);
                if (ev == ee) rank = basev[ee] + (int)__popcll(m & below);
                basev[ee] += (int)__popcll(m);      // wave-uniform
            }
            evk[ro] = ev; rkk[ro] = rank;
        }
        int startv[8];
        {
            int run = 0;
            #pragma unroll
            for (int ee = 0; ee < 8; ++ee) { startv[ee] = run; run += basev[ee]; }
        }
        #pragma unroll
        for (int ro = 0; ro < 2; ++ro) {
            int s = 0;
            #pragma unroll
            for (int ee = 0; ee < 8; ++ee) s += (ee < evk[ro]) ? basev[ee] : 0;
            int slot = s + rkk[ro];
            int tok = ro * 64 + lane;
            destR[r][tok] = slot;
            trowR[r][slot] = tok;
        }
        #pragma unroll
        for (int ee = 0; ee < 8; ++ee)
            if (lane == ee) { cntR[r][ee] = basev[ee]; startR[r][ee] = startv[ee]; }
    };

    // scatter xv (window lw) -> A[buf], bucketed + chunk-XOR swizzle
    auto SCATTER = [&](int lw, int buf) {
        const int r = lw & 3;
        #pragma unroll
        for (int rr = 0; rr < 8; ++rr) {
            int c = rr * 512 + tid;            // 16B chunk id (4096/window)
            int row = c >> 5;
            int s = destR[r][row];
            int fc = (c & 31) >> 1, half = c & 1;
            *(uint2*)(&A[buf][s * 128 + ((fc ^ (s & 7)) << 3) + half * 4]) =
                make_uint2(pack2(xv[rr].x, xv[rr].y), pack2(xv[rr].z, xv[rr].w));
        }
    };

    auto COMPUTE = [&](int t) {
        const int r = t & 3, buf = t & 1;
        const long tb = (long)(win0 + t) * NTOK;
        #pragma unroll
        for (int ee = 0; ee < 8; ++ee) {
            int cnt = cntR[r][ee];
            if (cnt == 0) continue;
            int st = startR[r][ee];
            for (int rb = st; rb < st + cnt; rb += 16) {
                int lim = st + cnt - rb; lim = lim < 16 ? lim : 16;
                int sr = rb + l15; sr = sr < NTOK ? sr : NTOK - 1;
                // A is stored in BUCKETED order: slot sr's row is at A[sr].
                f32x4 acc = {0.f, 0.f, 0.f, 0.f};
                #pragma unroll
                for (int kk = 0; kk < 4; ++kk) {
                    int fc = kk * 4 + lq;
                    bf16x8 a = *(const bf16x8*)(&A[buf][sr * 128 + ((fc ^ (sr & 7)) << 3)]);
                    acc = __builtin_amdgcn_mfma_f32_16x16x32_bf16(a, bf_[ee][kk], acc, 0, 0, 0);
                }
                #pragma unroll
                for (int rr = 0; rr < 4; ++rr) {
                    int ri = lq * 4 + rr;
                    if (ri < lim) {
                        int tok = trowR[r][rb + ri];   // slot -> token (store only)
                        out[(tb + tok) * 128 + w * 16 + l15] = acc[rr] + bv_[ee];
                    }
                }
            }
        }
    };

    // ---- prologue ----
    {
        int2 sv = *(const int2*)(split + (long)win0 * NTOK + tid * 2);
        sSplit[tid * 2] = sv.x; sSplit[tid * 2 + 1] = sv.y;
    }
    XISSUE(0);
    BARRIER();                       // sSplit visible
    if (w == 0) { META(0); META(1); }
    BARRIER();                       // meta 0,1 visible
    SCATTER(0, 0);                   // single counted vmcnt wait on xv(0)

    // ---- steady state ----
    for (int t = 0; t < ITERS; ++t) {
        BARRIER();                   // A[t&1] + meta(t) visible; bufs rotate
        if (t + 1 < ITERS) XISSUE(t + 1);
        if (w == 0 && t + 2 < ITERS) META(t + 2);
        COMPUTE(t);
        if (t + 1 < ITERS) SCATTER(t + 1, (t + 1) & 1);
    }
}

extern "C" void kernel_launch(void* const* d_in, const int* in_sizes, int n_in,
                              void* d_out, int out_size, void* d_ws, size_t ws_size,
                              hipStream_t stream) {
    const float* x     = (const float*)d_in[0];
    const int*   split = (const int*)d_in[1];
    const float* W     = (const float*)d_in[2];
    const float* bias  = (const float*)d_in[3];
    float* out = (float*)d_out;

    unsigned short* Wt = (unsigned short*)d_ws;   // 8*128*128 bf16 = 256 KB

    k_wt<<<64, 256, 0, stream>>>(W, Wt);
    k_fused<<<GRID, 512, 0, stream>>>(x, split, bias, Wt, out);
}